// Round 9
// baseline (232.062 us; speedup 1.0000x reference)
//
#include <hip/hip_runtime.h>

#define NN 50000
#define NE 1600000
#define IN_CH 128
#define HEADS 4
#define OUT_CH 32
#define HC 128                  // HEADS*OUT_CH
#define NEG_SLOPE 0.2f
#define EPS 1e-9f
#define SEG 96                  // csr slots per dst (Poisson(32), +11 sigma)
#define CSTR 8                  // cnt stride (ints): 4 counters per 128B line

#define FGRP 8                                   // fill dst-window groups
#define DPG (NN / FGRP)                          // 6250 dst nodes per group
#define FILL_BPG ((NE / 8 + 255) / 256)          // 782 blocks per group (8 e/thr)
#define ROWS_PB 64                               // rows per MFMA proj block
#define PROJ_BLOCKS ((NN + ROWS_PB - 1) / ROWS_PB)   // 782
#define XPITCH 136                               // LDS x row pitch (shorts)
#define INIT_BLOCKS ((NN + 255) / 256)           // 196
#define GMAX_BLOCKS ((NN + 255) / 256)           // 196

#define ENC_NEG_INF 0x007FFFFFu

using bf16x8 = __attribute__((ext_vector_type(8))) short;
using f32x4  = __attribute__((ext_vector_type(4))) float;
using u16x8  = __attribute__((ext_vector_type(8))) unsigned short;

__device__ __forceinline__ float leaky(float v) {
    return v >= 0.0f ? v : NEG_SLOPE * v;
}
__device__ __forceinline__ unsigned short f2bf(float f) {   // RNE bf16
    unsigned u = __float_as_uint(f);
    return (unsigned short)((u + 0x7fffu + ((u >> 16) & 1u)) >> 16);
}
__device__ __forceinline__ float bf2f(unsigned short b) {
    return __uint_as_float((unsigned)b << 16);
}
__device__ __forceinline__ unsigned int fenc(float f) {     // order-preserving
    unsigned int u = __float_as_uint(f);
    return (u & 0x80000000u) ? ~u : (u | 0x80000000u);
}
__device__ __forceinline__ float fdec(unsigned int u) {
    return (u & 0x80000000u) ? __uint_as_float(u & 0x7fffffffu)
                             : __uint_as_float(~u);
}

// ------------- init: cnt zero (CSTR-padded, FULL lines) + gmax + Wt ---------
// r8 mistake: zeroing only cnt[i*CSTR] = 50K scattered partial-line stores
// (RMW traffic). Now each thread writes its full 32B stripe (2x int4),
// coalesced full-line writes across the 1.6MB region.
__global__ __launch_bounds__(256) void k_init(int* __restrict__ cnt,
                                              unsigned int* __restrict__ gmax,
                                              const float* __restrict__ W,
                                              unsigned short* __restrict__ Wt_bf) {
    const int i = blockIdx.x * 256 + threadIdx.x;
    if (i < HEADS) gmax[i] = ENC_NEG_INF;
    if (i < NN) {
        const int4 z = make_int4(0, 0, 0, 0);
        *(int4*)(cnt + (size_t)i * CSTR) = z;
        *(int4*)(cnt + (size_t)i * CSTR + 4) = z;
    }
    if (i < IN_CH * HC) {
        int k = i >> 7, n = i & 127;
        Wt_bf[n * IN_CH + k] = f2bf(W[i]);
    }
}

// -------- MFMA projection (+fused logits) & windowed CSR fill ---------------
// Fill ledger (hard-won): windowed 8-group + packed cnt = 82us (r4);
// unwindowed = 125us (r5, L2 residency lost); per-wave fused gmax atomics =
// 189us (r7, same-line RMW serialization); windowed + CSTR=8 padded cnt =
// 77.9us (r8, BEST — 4 counters/128B line cuts same-line collisions 8x).
// Remaining floor is same-ADDRESS serialization (32 edges/counter) —
// irreducible in this algorithm.
// blocks [0, PROJ_BLOCKS): 4 waves, wave w rows [n0+16w, n0+16w+16).
// blocks [PROJ_BLOCKS, +FGRP*FILL_BPG): group f = fb&7 writes only dst in
//   [f*DPG,(f+1)*DPG) -> XCD-local cnt slice + ~1.2MB csr window L2-resident.
__global__ __launch_bounds__(256) void k_proj_fill(
        const float* __restrict__ x,
        const unsigned short* __restrict__ Wt_bf,
        const float* __restrict__ att_s, const float* __restrict__ att_d,
        unsigned short* __restrict__ h_bf,
        float* __restrict__ a_s, float* __restrict__ a_d,
        const int* __restrict__ ei, int* __restrict__ cnt,
        unsigned short* __restrict__ csr_src) {
    if (blockIdx.x >= PROJ_BLOCKS) {
        const int fb = blockIdx.x - PROJ_BLOCKS;
        const int f = fb & (FGRP - 1);
        const int bg = fb >> 3;
        const int e0 = (bg * 256 + (int)threadIdx.x) * 8;
        if (e0 >= NE) return;                    // NE%8==0 -> whole pack valid
        const int lo = f * DPG;
        const int4 d0 = *(const int4*)(ei + NE + e0);
        const int4 d1 = *(const int4*)(ei + NE + e0 + 4);
        const int4 s0 = *(const int4*)(ei + e0);
        const int4 s1 = *(const int4*)(ei + e0 + 4);
        const int d[8] = {d0.x, d0.y, d0.z, d0.w, d1.x, d1.y, d1.z, d1.w};
        const int s[8] = {s0.x, s0.y, s0.z, s0.w, s1.x, s1.y, s1.z, s1.w};
#pragma unroll
        for (int k = 0; k < 8; ++k) {
            if ((unsigned)(d[k] - lo) < (unsigned)DPG) {
                const int pos = atomicAdd(&cnt[(size_t)d[k] * CSTR], 1);
                if (pos < SEG)                   // statistically never false
                    csr_src[(size_t)d[k] * SEG + pos] = (unsigned short)s[k];
            }
        }
        return;
    }
    __shared__ short xs[ROWS_PB * XPITCH];
    const int tid = threadIdx.x;
    const int n0 = blockIdx.x * ROWS_PB;

#pragma unroll
    for (int it = 0; it < 8; ++it) {
        const int idx = it * 256 + tid;          // float4 index
        const int row = idx >> 5;                // 32 float4 per row
        const int k4 = idx & 31;
        float4 v = make_float4(0.f, 0.f, 0.f, 0.f);
        if (n0 + row < NN) v = *(const float4*)(x + (size_t)(n0 + row) * IN_CH + k4 * 4);
        short* p = &xs[row * XPITCH + k4 * 4];
        p[0] = (short)f2bf(v.x); p[1] = (short)f2bf(v.y);
        p[2] = (short)f2bf(v.z); p[3] = (short)f2bf(v.w);
    }
    __syncthreads();

    const int wave = tid >> 6;
    const int lane = tid & 63;
    const int quad = lane >> 4;
    const int m16 = lane & 15;
    const int wrow = wave * 16;

    bf16x8 a[4];
#pragma unroll
    for (int ks = 0; ks < 4; ++ks)
        a[ks] = *(const bf16x8*)&xs[(wrow + m16) * XPITCH + ks * 32 + quad * 8];

    const int row_base = n0 + wrow + quad * 4;
#pragma unroll
    for (int hh = 0; hh < 4; ++hh) {
        float psh[4] = {0.f, 0.f, 0.f, 0.f};
        float pdh[4] = {0.f, 0.f, 0.f, 0.f};
#pragma unroll
        for (int c2 = 0; c2 < 2; ++c2) {
            const int ct = hh * 2 + c2;
            const unsigned short* wb = Wt_bf + (size_t)(ct * 16 + m16) * IN_CH + quad * 8;
            bf16x8 b0 = *(const bf16x8*)(wb);
            bf16x8 b1 = *(const bf16x8*)(wb + 32);
            bf16x8 b2 = *(const bf16x8*)(wb + 64);
            bf16x8 b3 = *(const bf16x8*)(wb + 96);
            f32x4 acc = {0.f, 0.f, 0.f, 0.f};
            acc = __builtin_amdgcn_mfma_f32_16x16x32_bf16(a[0], b0, acc, 0, 0, 0);
            acc = __builtin_amdgcn_mfma_f32_16x16x32_bf16(a[1], b1, acc, 0, 0, 0);
            acc = __builtin_amdgcn_mfma_f32_16x16x32_bf16(a[2], b2, acc, 0, 0, 0);
            acc = __builtin_amdgcn_mfma_f32_16x16x32_bf16(a[3], b3, acc, 0, 0, 0);
            const int col = ct * 16 + m16;
            const float asv = att_s[col];
            const float adv = att_d[col];
#pragma unroll
            for (int r = 0; r < 4; ++r) {
                const int n = row_base + r;
                if (n < NN) h_bf[(size_t)n * HC + col] = f2bf(acc[r]);
                psh[r] = fmaf(acc[r], asv, psh[r]);
                pdh[r] = fmaf(acc[r], adv, pdh[r]);
            }
        }
#pragma unroll
        for (int mk = 1; mk <= 8; mk <<= 1) {
#pragma unroll
            for (int r = 0; r < 4; ++r) {
                psh[r] += __shfl_xor(psh[r], mk, 64);
                pdh[r] += __shfl_xor(pdh[r], mk, 64);
            }
        }
        if (m16 == 0) {
#pragma unroll
            for (int r = 0; r < 4; ++r) {
                const int n = row_base + r;
                if (n < NN) {
                    a_s[n * HEADS + hh] = psh[r];
                    a_d[n * HEADS + hh] = pdh[r];
                }
            }
        }
    }
}

// ------------------------------------ global per-head max of a_s ------------
__global__ __launch_bounds__(256) void k_gmax(const float* __restrict__ a_s,
                                              unsigned int* __restrict__ gmax) {
    const int n = blockIdx.x * 256 + threadIdx.x;
    float4 m4 = make_float4(-1e30f, -1e30f, -1e30f, -1e30f);
    if (n < NN) m4 = *(const float4*)(a_s + n * 4);
#pragma unroll
    for (int m = 32; m >= 1; m >>= 1) {
        m4.x = fmaxf(m4.x, __shfl_xor(m4.x, m, 64));
        m4.y = fmaxf(m4.y, __shfl_xor(m4.y, m, 64));
        m4.z = fmaxf(m4.z, __shfl_xor(m4.z, m, 64));
        m4.w = fmaxf(m4.w, __shfl_xor(m4.w, m, 64));
    }
    __shared__ float wm[4][4];
    const int wv = threadIdx.x >> 6;
    if ((threadIdx.x & 63) == 0) {
        wm[wv][0] = m4.x; wm[wv][1] = m4.y; wm[wv][2] = m4.z; wm[wv][3] = m4.w;
    }
    __syncthreads();
    if (threadIdx.x < 4) {
        float mm = fmaxf(fmaxf(wm[0][threadIdx.x], wm[1][threadIdx.x]),
                         fmaxf(wm[2][threadIdx.x], wm[3][threadIdx.x]));
        atomicMax(&gmax[threadIdx.x], fenc(mm));
    }
}

// ----------------------------------------------------- gather aggregation ---
// one wave per dst node; 16-lane quarter owns edge slots; lane owns 8
// channels (ushort8). r8 counters: 74.5us, 250MB past-L2 @3.35TB/s,
// VALU 42% — neither pipe saturated -> latency partially exposed with only
// 4 gathers in flight per wave. Now 2-slot x 2-deep rotated pipeline:
// slots A,B consumed; C,D prefetched; stride 8 -> 8 h-row gathers in
// flight/wave (+~8 VGPR, no occupancy impact at VGPR~32).
__global__ __launch_bounds__(256) void k_agg(const int* __restrict__ cnt,
                                             const unsigned short* __restrict__ csr_src,
                                             const unsigned short* __restrict__ h_bf,
                                             const float* __restrict__ a_s,
                                             const float* __restrict__ a_d,
                                             const unsigned int* __restrict__ gmax,
                                             const float* __restrict__ bias,
                                             float* __restrict__ out) {
    const int n = blockIdx.x * 4 + (threadIdx.x >> 6);
    const int lane = threadIdx.x & 63;
    if (n >= NN) return;
    const int q = lane >> 4;                      // quarter: owns slots i, i+4
    const int ql = lane & 15;                     // channels 8*ql .. 8*ql+7
    const int hd = ql >> 2;                       // head of those channels
    int dg = cnt[(size_t)n * CSTR];
    if (dg > SEG) dg = SEG;
    const int beg = n * SEG;
    const int end = beg + dg;

    const float ad_h = a_d[n * 4 + hd];
    const float bound = leaky(fdec(gmax[hd]) + ad_h);   // >= every edge score

    // self term (all 4 quads compute it -> pre-scale by 1/4; quad-reduce sums)
    float ev = 0.25f * __expf(leaky(a_s[n * 4 + hd] + ad_h) - bound);
    float denom = ev;
    const u16x8 hs = *(const u16x8*)(h_bf + (size_t)n * HC + 8 * ql);
    float acc[8];
#pragma unroll
    for (int k = 0; k < 8; ++k) acc[k] = ev * bf2f(hs[k]);

    // prologue: slots A=(i), B=(i+4); dummy src = n for out-of-range
    int i = beg + q;
    int sA = (i     < end) ? (int)csr_src[i]     : n;
    int sB = (i + 4 < end) ? (int)csr_src[i + 4] : n;
    float asA = a_s[sA * 4 + hd];
    u16x8 hA = *(const u16x8*)(h_bf + (size_t)sA * HC + 8 * ql);
    float asB = a_s[sB * 4 + hd];
    u16x8 hB = *(const u16x8*)(h_bf + (size_t)sB * HC + 8 * ql);

    for (; i < end; i += 8) {
        // prefetch next pair (C,D) while consuming (A,B)
        const int sC = (i + 8  < end) ? (int)csr_src[i + 8]  : n;
        const int sD = (i + 12 < end) ? (int)csr_src[i + 12] : n;
        const float asC = a_s[sC * 4 + hd];
        const u16x8 hC = *(const u16x8*)(h_bf + (size_t)sC * HC + 8 * ql);
        const float asD = a_s[sD * 4 + hd];
        const u16x8 hD = *(const u16x8*)(h_bf + (size_t)sD * HC + 8 * ql);

        const float eA = __expf(leaky(asA + ad_h) - bound);   // i < end: valid
        denom += eA;
#pragma unroll
        for (int k = 0; k < 8; ++k)
            acc[k] = fmaf(eA, bf2f(hA[k]), acc[k]);
        if (i + 4 < end) {
            const float eB = __expf(leaky(asB + ad_h) - bound);
            denom += eB;
#pragma unroll
            for (int k = 0; k < 8; ++k)
                acc[k] = fmaf(eB, bf2f(hB[k]), acc[k]);
        }
        asA = asC; hA = hC; asB = asD; hB = hD;
    }
#pragma unroll
    for (int k = 0; k < 8; ++k) {
        acc[k] += __shfl_xor(acc[k], 16, 64);
        acc[k] += __shfl_xor(acc[k], 32, 64);
    }
    denom += __shfl_xor(denom, 16, 64);
    denom += __shfl_xor(denom, 32, 64);

    if (q == 0) {
        const float inv = 1.0f / (denom + EPS);
        float* o = out + (size_t)n * HC + 8 * ql;
        const float* b = bias + 8 * ql;
        f32x4 o0, o1;
        o0[0] = acc[0] * inv + b[0]; o0[1] = acc[1] * inv + b[1];
        o0[2] = acc[2] * inv + b[2]; o0[3] = acc[3] * inv + b[3];
        o1[0] = acc[4] * inv + b[4]; o1[1] = acc[5] * inv + b[5];
        o1[2] = acc[6] * inv + b[6]; o1[3] = acc[7] * inv + b[7];
        __builtin_nontemporal_store(o0, (f32x4*)(o));
        __builtin_nontemporal_store(o1, (f32x4*)(o + 4));
    }
}

// ---------------------------------------------------------------------------
extern "C" void kernel_launch(void* const* d_in, const int* in_sizes, int n_in,
                              void* d_out, int out_size, void* d_ws, size_t ws_size,
                              hipStream_t stream) {
    const float* x     = (const float*)d_in[0];
    const int*   ei    = (const int*)d_in[1];
    const float* W     = (const float*)d_in[2];
    const float* att_s = (const float*)d_in[3];
    const float* att_d = (const float*)d_in[4];
    const float* bias  = (const float*)d_in[5];
    float* out = (float*)d_out;

    char* ws = (char*)d_ws;
    int*   cnt     = (int*)ws;    ws += (size_t)NN * CSTR * 4;         // 1.6 MB
    unsigned int* gmax = (unsigned int*)ws; ws += 64;
    unsigned short* csr_src = (unsigned short*)ws; ws += (size_t)NN * SEG * 2; // 9.6 MB
    unsigned short* h_bf = (unsigned short*)ws; ws += (size_t)NN * HC * 2; // 12.8 MB
    float* a_s     = (float*)ws;  ws += (size_t)NN * HEADS * 4;        // 0.8 MB
    float* a_d     = (float*)ws;  ws += (size_t)NN * HEADS * 4;        // 0.8 MB
    unsigned short* Wt_bf = (unsigned short*)ws; ws += (size_t)IN_CH * HC * 2; // 32 KB

    k_init     <<<INIT_BLOCKS, 256, 0, stream>>>(cnt, gmax, W, Wt_bf);
    k_proj_fill<<<PROJ_BLOCKS + FGRP * FILL_BPG, 256, 0, stream>>>(
        x, Wt_bf, att_s, att_d, h_bf, a_s, a_d, ei, cnt, csr_src);
    k_gmax     <<<GMAX_BLOCKS, 256, 0, stream>>>(a_s, gmax);
    k_agg      <<<(NN + 3) / 4, 256, 0, stream>>>(cnt, csr_src, h_bf, a_s, a_d,
                                                  gmax, bias, out);
}

// Round 10
// 213.020 us; speedup vs baseline: 1.0894x; 1.0894x over previous
//
#include <hip/hip_runtime.h>

#define NN 50000
#define NE 1600000
#define IN_CH 128
#define HEADS 4
#define OUT_CH 32
#define HC 128                  // HEADS*OUT_CH
#define NEG_SLOPE 0.2f
#define EPS 1e-9f
#define SEG 96                  // csr slots per dst (Poisson(32), +11 sigma)
#define CSTR 8                  // cnt stride (ints): 4 counters per 128B line

#define FGRP 8                                   // fill dst-window groups
#define DPG (NN / FGRP)                          // 6250 dst nodes per group
#define FILL_BPG ((NE / 8 + 255) / 256)          // 782 blocks per group (8 e/thr)
#define ROWS_PB 64                               // rows per MFMA proj block
#define PROJ_BLOCKS ((NN + ROWS_PB - 1) / ROWS_PB)   // 782
#define XPITCH 136                               // LDS x row pitch (shorts)
#define INIT_BLOCKS ((NN + 255) / 256)           // 196
#define GMAX_BLOCKS ((NN + 255) / 256)           // 196

#define ENC_NEG_INF 0x007FFFFFu

using bf16x8 = __attribute__((ext_vector_type(8))) short;
using f32x4  = __attribute__((ext_vector_type(4))) float;
using u16x8  = __attribute__((ext_vector_type(8))) unsigned short;

__device__ __forceinline__ float leaky(float v) {
    return v >= 0.0f ? v : NEG_SLOPE * v;
}
__device__ __forceinline__ unsigned short f2bf(float f) {   // RNE bf16
    unsigned u = __float_as_uint(f);
    return (unsigned short)((u + 0x7fffu + ((u >> 16) & 1u)) >> 16);
}
__device__ __forceinline__ float bf2f(unsigned short b) {
    return __uint_as_float((unsigned)b << 16);
}
__device__ __forceinline__ unsigned int fenc(float f) {     // order-preserving
    unsigned int u = __float_as_uint(f);
    return (u & 0x80000000u) ? ~u : (u | 0x80000000u);
}
__device__ __forceinline__ float fdec(unsigned int u) {
    return (u & 0x80000000u) ? __uint_as_float(u & 0x7fffffffu)
                             : __uint_as_float(~u);
}

// ------------- init: cnt zero (CSTR-padded, FULL lines) + gmax + Wt ---------
__global__ __launch_bounds__(256) void k_init(int* __restrict__ cnt,
                                              unsigned int* __restrict__ gmax,
                                              const float* __restrict__ W,
                                              unsigned short* __restrict__ Wt_bf) {
    const int i = blockIdx.x * 256 + threadIdx.x;
    if (i < HEADS) gmax[i] = ENC_NEG_INF;
    if (i < NN) {
        const int4 z = make_int4(0, 0, 0, 0);
        *(int4*)(cnt + (size_t)i * CSTR) = z;
        *(int4*)(cnt + (size_t)i * CSTR + 4) = z;
    }
    if (i < IN_CH * HC) {
        int k = i >> 7, n = i & 127;
        Wt_bf[n * IN_CH + k] = f2bf(W[i]);
    }
}

// -------- MFMA projection (+fused logits) & windowed CSR fill ---------------
// Fill ledger (final): windowed 8-group + packed cnt = 82us (r4); unwindowed
// = 125us (r5: L2 residency is the windowing's value); per-wave fused gmax
// atomics = 189us (r7: same-line RMW serialization); queue 2-phase = worse
// (r3); nt loads = worse (r1/r2); windowed + CSTR=8 padded cnt = 77.9-78.6us
// (r8/r9, BEST, stable). Remaining floor: same-ADDRESS atomic serialization
// (32 edges/counter) — irreducible in this one-pass-CSR algorithm.
__global__ __launch_bounds__(256) void k_proj_fill(
        const float* __restrict__ x,
        const unsigned short* __restrict__ Wt_bf,
        const float* __restrict__ att_s, const float* __restrict__ att_d,
        unsigned short* __restrict__ h_bf,
        float* __restrict__ a_s, float* __restrict__ a_d,
        const int* __restrict__ ei, int* __restrict__ cnt,
        unsigned short* __restrict__ csr_src) {
    if (blockIdx.x >= PROJ_BLOCKS) {
        const int fb = blockIdx.x - PROJ_BLOCKS;
        const int f = fb & (FGRP - 1);
        const int bg = fb >> 3;
        const int e0 = (bg * 256 + (int)threadIdx.x) * 8;
        if (e0 >= NE) return;                    // NE%8==0 -> whole pack valid
        const int lo = f * DPG;
        const int4 d0 = *(const int4*)(ei + NE + e0);
        const int4 d1 = *(const int4*)(ei + NE + e0 + 4);
        const int4 s0 = *(const int4*)(ei + e0);
        const int4 s1 = *(const int4*)(ei + e0 + 4);
        const int d[8] = {d0.x, d0.y, d0.z, d0.w, d1.x, d1.y, d1.z, d1.w};
        const int s[8] = {s0.x, s0.y, s0.z, s0.w, s1.x, s1.y, s1.z, s1.w};
#pragma unroll
        for (int k = 0; k < 8; ++k) {
            if ((unsigned)(d[k] - lo) < (unsigned)DPG) {
                const int pos = atomicAdd(&cnt[(size_t)d[k] * CSTR], 1);
                if (pos < SEG)                   // statistically never false
                    csr_src[(size_t)d[k] * SEG + pos] = (unsigned short)s[k];
            }
        }
        return;
    }
    __shared__ short xs[ROWS_PB * XPITCH];
    const int tid = threadIdx.x;
    const int n0 = blockIdx.x * ROWS_PB;

#pragma unroll
    for (int it = 0; it < 8; ++it) {
        const int idx = it * 256 + tid;          // float4 index
        const int row = idx >> 5;                // 32 float4 per row
        const int k4 = idx & 31;
        float4 v = make_float4(0.f, 0.f, 0.f, 0.f);
        if (n0 + row < NN) v = *(const float4*)(x + (size_t)(n0 + row) * IN_CH + k4 * 4);
        short* p = &xs[row * XPITCH + k4 * 4];
        p[0] = (short)f2bf(v.x); p[1] = (short)f2bf(v.y);
        p[2] = (short)f2bf(v.z); p[3] = (short)f2bf(v.w);
    }
    __syncthreads();

    const int wave = tid >> 6;
    const int lane = tid & 63;
    const int quad = lane >> 4;
    const int m16 = lane & 15;
    const int wrow = wave * 16;

    bf16x8 a[4];
#pragma unroll
    for (int ks = 0; ks < 4; ++ks)
        a[ks] = *(const bf16x8*)&xs[(wrow + m16) * XPITCH + ks * 32 + quad * 8];

    const int row_base = n0 + wrow + quad * 4;
#pragma unroll
    for (int hh = 0; hh < 4; ++hh) {
        float psh[4] = {0.f, 0.f, 0.f, 0.f};
        float pdh[4] = {0.f, 0.f, 0.f, 0.f};
#pragma unroll
        for (int c2 = 0; c2 < 2; ++c2) {
            const int ct = hh * 2 + c2;
            const unsigned short* wb = Wt_bf + (size_t)(ct * 16 + m16) * IN_CH + quad * 8;
            bf16x8 b0 = *(const bf16x8*)(wb);
            bf16x8 b1 = *(const bf16x8*)(wb + 32);
            bf16x8 b2 = *(const bf16x8*)(wb + 64);
            bf16x8 b3 = *(const bf16x8*)(wb + 96);
            f32x4 acc = {0.f, 0.f, 0.f, 0.f};
            acc = __builtin_amdgcn_mfma_f32_16x16x32_bf16(a[0], b0, acc, 0, 0, 0);
            acc = __builtin_amdgcn_mfma_f32_16x16x32_bf16(a[1], b1, acc, 0, 0, 0);
            acc = __builtin_amdgcn_mfma_f32_16x16x32_bf16(a[2], b2, acc, 0, 0, 0);
            acc = __builtin_amdgcn_mfma_f32_16x16x32_bf16(a[3], b3, acc, 0, 0, 0);
            const int col = ct * 16 + m16;
            const float asv = att_s[col];
            const float adv = att_d[col];
#pragma unroll
            for (int r = 0; r < 4; ++r) {
                const int n = row_base + r;
                if (n < NN) h_bf[(size_t)n * HC + col] = f2bf(acc[r]);
                psh[r] = fmaf(acc[r], asv, psh[r]);
                pdh[r] = fmaf(acc[r], adv, pdh[r]);
            }
        }
#pragma unroll
        for (int mk = 1; mk <= 8; mk <<= 1) {
#pragma unroll
            for (int r = 0; r < 4; ++r) {
                psh[r] += __shfl_xor(psh[r], mk, 64);
                pdh[r] += __shfl_xor(pdh[r], mk, 64);
            }
        }
        if (m16 == 0) {
#pragma unroll
            for (int r = 0; r < 4; ++r) {
                const int n = row_base + r;
                if (n < NN) {
                    a_s[n * HEADS + hh] = psh[r];
                    a_d[n * HEADS + hh] = pdh[r];
                }
            }
        }
    }
}

// --------- global per-head max of a_s + cnt compaction for k_agg ------------
// Compaction: k_agg must not pay the strided cnt[n*CSTR] read (suspect for
// the r8/r9 +12us vs r4's packed-cnt agg). This kernel touches every n
// anyway; emit packed cnt_p[n] = min(cnt[n*CSTR], SEG).
__global__ __launch_bounds__(256) void k_gmax(const float* __restrict__ a_s,
                                              const int* __restrict__ cnt,
                                              int* __restrict__ cnt_p,
                                              unsigned int* __restrict__ gmax) {
    const int n = blockIdx.x * 256 + threadIdx.x;
    float4 m4 = make_float4(-1e30f, -1e30f, -1e30f, -1e30f);
    if (n < NN) {
        m4 = *(const float4*)(a_s + n * 4);
        int c = cnt[(size_t)n * CSTR];
        cnt_p[n] = c > SEG ? SEG : c;
    }
#pragma unroll
    for (int m = 32; m >= 1; m >>= 1) {
        m4.x = fmaxf(m4.x, __shfl_xor(m4.x, m, 64));
        m4.y = fmaxf(m4.y, __shfl_xor(m4.y, m, 64));
        m4.z = fmaxf(m4.z, __shfl_xor(m4.z, m, 64));
        m4.w = fmaxf(m4.w, __shfl_xor(m4.w, m, 64));
    }
    __shared__ float wm[4][4];
    const int wv = threadIdx.x >> 6;
    if ((threadIdx.x & 63) == 0) {
        wm[wv][0] = m4.x; wm[wv][1] = m4.y; wm[wv][2] = m4.z; wm[wv][3] = m4.w;
    }
    __syncthreads();
    if (threadIdx.x < 4) {
        float mm = fmaxf(fmaxf(wm[0][threadIdx.x], wm[1][threadIdx.x]),
                         fmaxf(wm[2][threadIdx.x], wm[3][threadIdx.x]));
        atomicMax(&gmax[threadIdx.x], fenc(mm));
    }
}

// ----------------------------------------------------- gather aggregation ---
// one wave per dst node; 16-lane quarter owns an edge (4 edges in flight);
// lane owns 8 channels (ushort8). Packed cnt_p. 1-deep rotated pipeline
// (r3/r4-measured 74.5us; r9's 2-deep variant showed NO gain -> fabric
// floor ~3.4TB/s on the random 256B h-row gathers, reverted).
__global__ __launch_bounds__(256) void k_agg(const int* __restrict__ cnt_p,
                                             const unsigned short* __restrict__ csr_src,
                                             const unsigned short* __restrict__ h_bf,
                                             const float* __restrict__ a_s,
                                             const float* __restrict__ a_d,
                                             const unsigned int* __restrict__ gmax,
                                             const float* __restrict__ bias,
                                             float* __restrict__ out) {
    const int n = blockIdx.x * 4 + (threadIdx.x >> 6);
    const int lane = threadIdx.x & 63;
    if (n >= NN) return;
    const int q = lane >> 4;                      // quarter: owns edges i+q
    const int ql = lane & 15;                     // channels 8*ql .. 8*ql+7
    const int hd = ql >> 2;                       // head of those channels
    const int dg = cnt_p[n];
    const int beg = n * SEG;
    const int end = beg + dg;

    const float ad_h = a_d[n * 4 + hd];
    const float bound = leaky(fdec(gmax[hd]) + ad_h);   // >= every edge score

    // self term (all 4 quads compute it -> pre-scale by 1/4; quad-reduce sums)
    float ev = 0.25f * __expf(leaky(a_s[n * 4 + hd] + ad_h) - bound);
    float denom = ev;
    const u16x8 hs = *(const u16x8*)(h_bf + (size_t)n * HC + 8 * ql);
    float acc[8];
#pragma unroll
    for (int k = 0; k < 8; ++k) acc[k] = ev * bf2f(hs[k]);

    // pipeline prologue: s0 (current), s1 (next); dummy = n (always valid)
    int i = beg + q;
    int s0v = (i < end)     ? (int)csr_src[i]     : n;
    int s1v = (i + 4 < end) ? (int)csr_src[i + 4] : n;
    float as0 = a_s[s0v * 4 + hd];
    u16x8 hv0 = *(const u16x8*)(h_bf + (size_t)s0v * HC + 8 * ql);

    for (; i < end; i += 4) {
        const int s2v = (i + 8 < end) ? (int)csr_src[i + 8] : n;
        const float as1 = a_s[s1v * 4 + hd];
        const u16x8 hv1 = *(const u16x8*)(h_bf + (size_t)s1v * HC + 8 * ql);
        const float e = __expf(leaky(as0 + ad_h) - bound);
        denom += e;
#pragma unroll
        for (int k = 0; k < 8; ++k)
            acc[k] = fmaf(e, bf2f(hv0[k]), acc[k]);
        as0 = as1; hv0 = hv1; s1v = s2v;
    }
#pragma unroll
    for (int k = 0; k < 8; ++k) {
        acc[k] += __shfl_xor(acc[k], 16, 64);
        acc[k] += __shfl_xor(acc[k], 32, 64);
    }
    denom += __shfl_xor(denom, 16, 64);
    denom += __shfl_xor(denom, 32, 64);

    if (q == 0) {
        const float inv = 1.0f / (denom + EPS);
        float* o = out + (size_t)n * HC + 8 * ql;
        const float* b = bias + 8 * ql;
        f32x4 o0, o1;
        o0[0] = acc[0] * inv + b[0]; o0[1] = acc[1] * inv + b[1];
        o0[2] = acc[2] * inv + b[2]; o0[3] = acc[3] * inv + b[3];
        o1[0] = acc[4] * inv + b[4]; o1[1] = acc[5] * inv + b[5];
        o1[2] = acc[6] * inv + b[6]; o1[3] = acc[7] * inv + b[7];
        __builtin_nontemporal_store(o0, (f32x4*)(o));
        __builtin_nontemporal_store(o1, (f32x4*)(o + 4));
    }
}

// ---------------------------------------------------------------------------
extern "C" void kernel_launch(void* const* d_in, const int* in_sizes, int n_in,
                              void* d_out, int out_size, void* d_ws, size_t ws_size,
                              hipStream_t stream) {
    const float* x     = (const float*)d_in[0];
    const int*   ei    = (const int*)d_in[1];
    const float* W     = (const float*)d_in[2];
    const float* att_s = (const float*)d_in[3];
    const float* att_d = (const float*)d_in[4];
    const float* bias  = (const float*)d_in[5];
    float* out = (float*)d_out;

    char* ws = (char*)d_ws;
    int*   cnt     = (int*)ws;    ws += (size_t)NN * CSTR * 4;         // 1.6 MB
    int*   cnt_p   = (int*)ws;    ws += (size_t)NN * 4;                // 200 KB
    unsigned int* gmax = (unsigned int*)ws; ws += 64;
    unsigned short* csr_src = (unsigned short*)ws; ws += (size_t)NN * SEG * 2; // 9.6 MB
    unsigned short* h_bf = (unsigned short*)ws; ws += (size_t)NN * HC * 2; // 12.8 MB
    float* a_s     = (float*)ws;  ws += (size_t)NN * HEADS * 4;        // 0.8 MB
    float* a_d     = (float*)ws;  ws += (size_t)NN * HEADS * 4;        // 0.8 MB
    unsigned short* Wt_bf = (unsigned short*)ws; ws += (size_t)IN_CH * HC * 2; // 32 KB

    k_init     <<<INIT_BLOCKS, 256, 0, stream>>>(cnt, gmax, W, Wt_bf);
    k_proj_fill<<<PROJ_BLOCKS + FGRP * FILL_BPG, 256, 0, stream>>>(
        x, Wt_bf, att_s, att_d, h_bf, a_s, a_d, ei, cnt, csr_src);
    k_gmax     <<<GMAX_BLOCKS, 256, 0, stream>>>(a_s, cnt, cnt_p, gmax);
    k_agg      <<<(NN + 3) / 4, 256, 0, stream>>>(cnt_p, csr_src, h_bf, a_s, a_d,
                                                  gmax, bias, out);
}